// Round 16
// baseline (4566.433 us; speedup 1.0000x reference)
//
#include <hip/hip_runtime.h>
#include <cstdint>
#include <cmath>

constexpr int BATCH = 64;
constexpr int T     = 512;
constexpr int N     = 1024;
constexpr int NWG   = 256;   // persistent workgroups (== CU count)
constexpr int NG    = 16;    // batch groups (4 batches each)
constexpr int GM    = 32;    // member WGs per group (16 per k-half)

typedef float f4 __attribute__((ext_vector_type(4)));
typedef float f2 __attribute__((ext_vector_type(2)));

struct alignas(128) PadInt { int v; int pad[31]; };
__device__ PadInt g_cnt2[NG * 2];  // per-(group, k-half) cumulative arrivals

// ---- MALL-coherent access helpers (bypass L1+L2) ---------------------------
__device__ __forceinline__ f4 ld_sys_x4(const float* p) {
  f4 v;
  asm volatile("global_load_dwordx4 %0, %1, off sc0 sc1" : "=v"(v) : "v"(p));
  return v;  // NOT ready until wait_vm0()
}
__device__ __forceinline__ int ld_sys_i32(const int* p) {
  int v;
  asm volatile("global_load_dword %0, %1, off sc0 sc1\n\ts_waitcnt vmcnt(0)"
               : "=v"(v) : "v"(p) : "memory");
  return v;
}
__device__ __forceinline__ void st_sys_x2(float* p, f2 v) {
  asm volatile("global_store_dwordx2 %0, %1, off sc0 sc1 nt" ::"v"(p), "v"(v)
               : "memory");
}
__device__ __forceinline__ void wait_vm0(void) {
  asm volatile("s_waitcnt vmcnt(0)" ::: "memory");
  __builtin_amdgcn_sched_barrier(0);
}
// blind arrive: result unused -> no round-trip wait on this wave
__device__ __forceinline__ void arrive_blind(int g, int half) {
  __hip_atomic_fetch_add(&g_cnt2[g * 2 + half].v, 1, __ATOMIC_RELAXED,
                         __HIP_MEMORY_SCOPE_AGENT);
}

// ---------------------------------------------------------------------------
// W_self = 0.5*(W + W^T); also re-initializes the barrier counters.
// ---------------------------------------------------------------------------
__global__ __launch_bounds__(256) void symm_k(const float* __restrict__ W,
                                              float* __restrict__ Ws) {
  if (blockIdx.x == 0 && blockIdx.y == 0 && threadIdx.x < NG * 2) {
    __hip_atomic_store(&g_cnt2[threadIdx.x].v, 0, __ATOMIC_RELAXED,
                       __HIP_MEMORY_SCOPE_AGENT);
  }
  int j = blockIdx.x * 16 + (threadIdx.x & 15);
  int i = blockIdx.y * 16 + (threadIdx.x >> 4);
  Ws[(size_t)i * N + j] = 0.5f * (W[(size_t)i * N + j] + W[(size_t)j * N + i]);
}

// ---------------------------------------------------------------------------
// x_proj = A (M x K) . B^T, B = W_input (N x K) row-major. 128x128 tile.
// XCD-aware swizzle: each XCD owns a contiguous bm chunk x all 8 bn.
// ---------------------------------------------------------------------------
__global__ __launch_bounds__(256) void xproj_gemm(const float* __restrict__ A,
                                                  const float* __restrict__ B,
                                                  float* __restrict__ C,
                                                  int M) {
  constexpr int BM = 128, BN = 128, BK = 16;
  __shared__ float As[BK][BM + 4];
  __shared__ float Bs[BK][BN + 4];

  const int tid = threadIdx.x;
  const int lin = blockIdx.x + gridDim.x * blockIdx.y;  // 0..2047
  const int sw  = ((lin & 7) << 8) + (lin >> 3);        // bijective (2048%8==0)
  const int bm  = sw >> 3;                              // 0..255
  const int bn  = sw & 7;                               // 0..7
  const int tx = tid & 15, ty = tid >> 4;
  const int K = N;

  float acc[8][8];
#pragma unroll
  for (int i = 0; i < 8; ++i)
#pragma unroll
    for (int j = 0; j < 8; ++j) acc[i][j] = 0.f;

  for (int kt = 0; kt < K; kt += BK) {
#pragma unroll
    for (int s = 0; s < 2; ++s) {
      int f = tid + s * 256;
      int row = f >> 2, kq = f & 3;
      float4 a = *reinterpret_cast<const float4*>(
          &A[(size_t)(bm * BM + row) * K + kt + kq * 4]);
      As[kq * 4 + 0][row] = a.x;
      As[kq * 4 + 1][row] = a.y;
      As[kq * 4 + 2][row] = a.z;
      As[kq * 4 + 3][row] = a.w;
      float4 b = *reinterpret_cast<const float4*>(
          &B[(size_t)(bn * BN + row) * K + kt + kq * 4]);
      Bs[kq * 4 + 0][row] = b.x;
      Bs[kq * 4 + 1][row] = b.y;
      Bs[kq * 4 + 2][row] = b.z;
      Bs[kq * 4 + 3][row] = b.w;
    }
    __syncthreads();

#pragma unroll
    for (int k = 0; k < BK; ++k) {
      float a[8], b[8];
      *reinterpret_cast<float4*>(&a[0]) =
          *reinterpret_cast<const float4*>(&As[k][ty * 8]);
      *reinterpret_cast<float4*>(&a[4]) =
          *reinterpret_cast<const float4*>(&As[k][ty * 8 + 4]);
      *reinterpret_cast<float4*>(&b[0]) =
          *reinterpret_cast<const float4*>(&Bs[k][tx * 8]);
      *reinterpret_cast<float4*>(&b[4]) =
          *reinterpret_cast<const float4*>(&Bs[k][tx * 8 + 4]);
#pragma unroll
      for (int i = 0; i < 8; ++i)
#pragma unroll
        for (int j = 0; j < 8; ++j) acc[i][j] = fmaf(a[i], b[j], acc[i][j]);
    }
    __syncthreads();
  }

#pragma unroll
  for (int i = 0; i < 8; ++i) {
    size_t row = (size_t)bm * BM + ty * 8 + i;
#pragma unroll
    for (int j = 0; j < 8; j += 4) {
      *reinterpret_cast<float4*>(&C[row * N + bn * BN + tx * 8 + j]) =
          *reinterpret_cast<const float4*>(&acc[i][j]);
    }
  }
}

// ---------------------------------------------------------------------------
// Persistent recurrence: R13 structure + SPLIT-HALF barriers.
// 256 WGs x 384 thr, 1 WG/CU (LDS ~85 KiB).  WG (p=wg&7, cg=wg>>3):
// cols cg*32..+31 for batch groups gA=2p, gB=2p+1 (4 batches each).
// k-halves have disjoint producers: cols 0-511 <- cg 0..15 (half 0),
// 512-1023 <- cg 16..31 (half 1).  Sync wave: blind-add own half ->
// poll half-0 (16 arrivals) -> stage lo 8KB -> ready1 -> poll half-1 ->
// stage hi -> ready2.  Compute waves: j 0..7 after ready1, j 8..15 after
// ready2 -- hi-half poll+stage hides under lo-half FMAs.  Compute waves
// remain MALL-minimal (LDS spins + own stores only).  Data path sc0+sc1 /
// nt write-through (MALL-coherent), R7+ lineage.
// ---------------------------------------------------------------------------
__global__ __launch_bounds__(384, 1) void rnn_persist(
    float* __restrict__ out, const float* __restrict__ Ws) {
  const int tid = threadIdx.x;
  const int wg  = blockIdx.x;
  const int p   = wg & 7;
  const int cg  = wg >> 3;
  const int m0  = cg * 32;
  const int gA  = 2 * p, gB = 2 * p + 1;
  const int b0A = gA * 4, b0B = gB * 4;
  const int half = (cg >= 16) ? 1 : 0;
  const size_t TN = (size_t)T * N;

  __shared__ __align__(16) char lds_raw[84992];
  __shared__ int lflags[64];
  // [0]=ready1A [4]=ready2A [16]=ready1B [20]=ready2B [32]=cntA [48]=cntB
  float (*hA)[1028] = reinterpret_cast<float(*)[1028]>(lds_raw);
  float (*hB)[1028] = reinterpret_cast<float(*)[1028]>(lds_raw + 16448);
  float* xplA = reinterpret_cast<float*>(lds_raw + 32896);
  float* xplB = reinterpret_cast<float*>(lds_raw + 33408);
  float (*Wq)[1028] = reinterpret_cast<float(*)[1028]>(lds_raw);

  if (tid == 0) {
    lflags[0] = -1; lflags[4] = -1; lflags[16] = -1; lflags[20] = -1;
    lflags[32] = 0; lflags[48] = 0;
  }
  __syncthreads();

  const int l  = tid & 63;
  const int v  = tid >> 6;          // 0-3 compute, 4-5 sync
  const int c2 = l & 3;
  const int kp = l >> 2;            // k partition (16-way)
  const int clocal = v * 8 + c2 * 2;  // compute waves: local col pair base

  // ---- W -> wreg in 4 quarters of 8 rows (overlay on h region) ----
  f4 wreg[2][16];
  for (int quarter = 0; quarter < 4; ++quarter) {
    if (tid < 256) {
#pragma unroll
      for (int q = 0; q < 8; ++q)
        *reinterpret_cast<float4*>(&Wq[q][tid * 4]) =
            *reinterpret_cast<const float4*>(
                &Ws[(size_t)(m0 + quarter * 8 + q) * N + tid * 4]);
    }
    __syncthreads();
    if (v == quarter) {
#pragma unroll
      for (int ci = 0; ci < 2; ++ci)
#pragma unroll
        for (int j = 0; j < 16; ++j)
          wreg[ci][j] =
              *reinterpret_cast<const f4*>(&Wq[c2 * 2 + ci][kp * 4 + 64 * j]);
    }
    __syncthreads();
  }

  if (v < 4) {
    // ================= COMPUTE WAVES =================
    float* obA[4];
    float* obB[4];
#pragma unroll
    for (int bi = 0; bi < 4; ++bi) {
      obA[bi] = out + (size_t)(b0A + bi) * TN + m0 + clocal;
      obB[bi] = out + (size_t)(b0B + bi) * TN + m0 + clocal;
    }

    auto do_chain = [&](float (*hX)[1028], float* xplX, float* const* obX,
                        int rdy1, int rdy2, int cntIdx, int t) {
      while (*(volatile int*)&lflags[rdy1] < t) __builtin_amdgcn_s_sleep(1);
      __builtin_amdgcn_fence(__ATOMIC_ACQUIRE, "workgroup");
      float acc[8];
#pragma unroll
      for (int i = 0; i < 8; ++i) acc[i] = 0.f;
      if (t > 0) {
#pragma unroll
        for (int j = 0; j < 8; ++j) {  // k in [0,512) -- half 0
          const int kb = kp * 4 + 64 * j;
          f4 hv[4];
#pragma unroll
          for (int bi = 0; bi < 4; ++bi)
            hv[bi] = *reinterpret_cast<const f4*>(&hX[bi][kb]);
#pragma unroll
          for (int bi = 0; bi < 4; ++bi)
#pragma unroll
            for (int ci = 0; ci < 2; ++ci) {
              float a = acc[bi * 2 + ci];
              a = fmaf(hv[bi].x, wreg[ci][j].x, a);
              a = fmaf(hv[bi].y, wreg[ci][j].y, a);
              a = fmaf(hv[bi].z, wreg[ci][j].z, a);
              a = fmaf(hv[bi].w, wreg[ci][j].w, a);
              acc[bi * 2 + ci] = a;
            }
        }
      }
      while (*(volatile int*)&lflags[rdy2] < t) __builtin_amdgcn_s_sleep(1);
      __builtin_amdgcn_fence(__ATOMIC_ACQUIRE, "workgroup");
      if (t > 0) {
#pragma unroll
        for (int j = 8; j < 16; ++j) {  // k in [512,1024) -- half 1
          const int kb = kp * 4 + 64 * j;
          f4 hv[4];
#pragma unroll
          for (int bi = 0; bi < 4; ++bi)
            hv[bi] = *reinterpret_cast<const f4*>(&hX[bi][kb]);
#pragma unroll
          for (int bi = 0; bi < 4; ++bi)
#pragma unroll
            for (int ci = 0; ci < 2; ++ci) {
              float a = acc[bi * 2 + ci];
              a = fmaf(hv[bi].x, wreg[ci][j].x, a);
              a = fmaf(hv[bi].y, wreg[ci][j].y, a);
              a = fmaf(hv[bi].z, wreg[ci][j].z, a);
              a = fmaf(hv[bi].w, wreg[ci][j].w, a);
              acc[bi * 2 + ci] = a;
            }
        }
#pragma unroll
        for (int o = 4; o < 64; o <<= 1)
#pragma unroll
          for (int i = 0; i < 8; ++i) acc[i] += __shfl_xor(acc[i], o, 64);
      }
      if (kp == 0) {
#pragma unroll
        for (int bi = 0; bi < 4; ++bi) {
          float x0 = xplX[bi * 32 + clocal];
          float x1 = xplX[bi * 32 + clocal + 1];
          f2 r;
          r.x = tanhf((t > 0 ? acc[bi * 2 + 0] : 0.f) + x0);
          r.y = tanhf((t > 0 ? acc[bi * 2 + 1] : 0.f) + x1);
          st_sys_x2(obX[bi] + (size_t)t * N, r);
        }
      }
      wait_vm0();  // this wave's stores acked at MALL
      if (l == 0) atomicAdd(&lflags[cntIdx], 1);
    };

    for (int t = 0; t < T; ++t) {
      do_chain(hA, xplA, obA, 0, 4, 32, t);
      do_chain(hB, xplB, obB, 16, 20, 48, t);
    }
  } else {
    // ================= SYNC/STAGE WAVES (split-half pipeline) =============
    const bool isB = (tid >= 320);
    const int lane = l;
    const int g    = isB ? gB : gA;
    const int b0   = isB ? b0B : b0A;
    float (*hb)[1028] = isB ? hB : hA;
    float* xpl = isB ? xplB : xplA;
    volatile int* ready1 = isB ? (volatile int*)&lflags[16]
                               : (volatile int*)&lflags[0];
    volatile int* ready2 = isB ? (volatile int*)&lflags[20]
                               : (volatile int*)&lflags[4];
    volatile int* cnt = isB ? (volatile int*)&lflags[48]
                            : (volatile int*)&lflags[32];

    const int r = lane >> 4;   // h row 0..3 (16 lanes per row)
    const int c = lane & 15;
    const float* hrow = out + (size_t)(b0 + r) * TN;
    const int xr = lane >> 3, xc = (lane & 7) * 4;  // lane<32: 4 rows x 32 col
    const float* xsrc = out + (size_t)(b0 + xr) * TN + m0 + xc;

    // t = 0: stage xp(0) only; open both ready flags
    {
      f4 xv;
      if (lane < 32) xv = ld_sys_x4(xsrc);
      wait_vm0();
      if (lane < 32) *reinterpret_cast<f4*>(&xpl[xr * 32 + xc]) = xv;
      __builtin_amdgcn_fence(__ATOMIC_RELEASE, "workgroup");
      if (lane == 0) { *ready1 = 0; *ready2 = 0; }
    }

    for (int t = 1; t < T; ++t) {
      if (lane == 0) {
        while (*cnt < 4 * t) __builtin_amdgcn_s_sleep(1);  // local acks(t-1)
        arrive_blind(g, half);                             // one blind add
        // wait for half-0 producers (16 arrivals)
        while (ld_sys_i32(&g_cnt2[g * 2 + 0].v) < 16 * t)
          __builtin_amdgcn_s_sleep(1);
      }
      const float* hs = hrow + (size_t)(t - 1) * N;
      f4 tmp[8];
      f4 xv;
      // ---- lo half: k in [0,512) + xp(t) ----
#pragma unroll
      for (int q = 0; q < 8; ++q) tmp[q] = ld_sys_x4(hs + 4 * (c + 16 * q));
      if (lane < 32) xv = ld_sys_x4(xsrc + (size_t)t * N);
      wait_vm0();
#pragma unroll
      for (int q = 0; q < 8; ++q)
        *reinterpret_cast<f4*>(&hb[r][4 * (c + 16 * q)]) = tmp[q];
      if (lane < 32) *reinterpret_cast<f4*>(&xpl[xr * 32 + xc]) = xv;
      __builtin_amdgcn_fence(__ATOMIC_RELEASE, "workgroup");
      if (lane == 0) *ready1 = t;

      // ---- hi half: k in [512,1024) (poll overlaps consumers' lo FMAs) ----
      if (lane == 0) {
        while (ld_sys_i32(&g_cnt2[g * 2 + 1].v) < 16 * t)
          __builtin_amdgcn_s_sleep(1);
      }
#pragma unroll
      for (int q = 8; q < 16; ++q)
        tmp[q - 8] = ld_sys_x4(hs + 4 * (c + 16 * q));
      wait_vm0();
#pragma unroll
      for (int q = 8; q < 16; ++q)
        *reinterpret_cast<f4*>(&hb[r][4 * (c + 16 * q)]) = tmp[q - 8];
      __builtin_amdgcn_fence(__ATOMIC_RELEASE, "workgroup");
      if (lane == 0) *ready2 = t;
    }
  }
}

// ---------------------------------------------------------------------------
extern "C" void kernel_launch(void* const* d_in, const int* in_sizes, int n_in,
                              void* d_out, int out_size, void* d_ws,
                              size_t ws_size, hipStream_t stream) {
  const float* in_seq  = (const float*)d_in[0];  // (64,512,1024)
  const float* W_lower = (const float*)d_in[1];  // (1024,1024)
  const float* W_input = (const float*)d_in[2];  // (1024,1024)
  float* out = (float*)d_out;                    // (64,512,1024)
  float* Ws  = (float*)d_ws;                     // 4 MiB scratch

  symm_k<<<dim3(N / 16, N / 16), 256, 0, stream>>>(W_lower, Ws);
  xproj_gemm<<<dim3(N / 128, (BATCH * T) / 128), 256, 0, stream>>>(
      in_seq, W_input, out, BATCH * T);
  rnn_persist<<<NWG, 384, 0, stream>>>(out, Ws);
}

// Round 17
// 2937.364 us; speedup vs baseline: 1.5546x; 1.5546x over previous
//
#include <hip/hip_runtime.h>
#include <cstdint>
#include <cmath>

constexpr int BATCH = 64;
constexpr int T     = 512;
constexpr int N     = 1024;
constexpr int NWG   = 256;   // persistent workgroups (== CU count)
constexpr int NG    = 32;    // batch groups (2 batches each)
constexpr int GM    = 16;    // member WGs per group

typedef float f4 __attribute__((ext_vector_type(4)));
typedef float f2 __attribute__((ext_vector_type(2)));

struct alignas(128) PadInt { int v; int pad[31]; };
__device__ PadInt g_cnt[NG];   // per-group cumulative arrival counters
__device__ PadInt g_flag[NG];  // per-group completed-step counters

// ---- MALL-coherent access helpers (bypass L1+L2) ---------------------------
__device__ __forceinline__ f4 ld_sys_x4(const float* p) {
  f4 v;
  asm volatile("global_load_dwordx4 %0, %1, off sc0 sc1" : "=v"(v) : "v"(p));
  return v;  // NOT ready until wait_vm0()
}
__device__ __forceinline__ int ld_sys_i32(const int* p) {
  int v;
  asm volatile("global_load_dword %0, %1, off sc0 sc1\n\ts_waitcnt vmcnt(0)"
               : "=v"(v) : "v"(p) : "memory");
  return v;
}
__device__ __forceinline__ void st_sys_x2(float* p, f2 v) {
  asm volatile("global_store_dwordx2 %0, %1, off sc0 sc1 nt" ::"v"(p), "v"(v)
               : "memory");
}
__device__ __forceinline__ void wait_vm0(void) {
  asm volatile("s_waitcnt vmcnt(0)" ::: "memory");
  __builtin_amdgcn_sched_barrier(0);
}

__device__ __forceinline__ void arrive_cnt(int g, int t) {
  int old = __hip_atomic_fetch_add(&g_cnt[g].v, 1, __ATOMIC_RELAXED,
                                   __HIP_MEMORY_SCOPE_AGENT);
  if (old == t * GM + (GM - 1))  // last arriver of this step: publish
    __hip_atomic_store(&g_flag[g].v, t + 1, __ATOMIC_RELAXED,
                       __HIP_MEMORY_SCOPE_AGENT);
}
__device__ __forceinline__ void pollf(int g, int e) {
  while (ld_sys_i32(&g_flag[g].v) < e) __builtin_amdgcn_s_sleep(1);
}

// ---------------------------------------------------------------------------
// W_self = 0.5*(W + W^T); also re-initializes the barrier state.
// ---------------------------------------------------------------------------
__global__ __launch_bounds__(256) void symm_k(const float* __restrict__ W,
                                              float* __restrict__ Ws) {
  if (blockIdx.x == 0 && blockIdx.y == 0 && threadIdx.x < NG) {
    __hip_atomic_store(&g_cnt[threadIdx.x].v, 0, __ATOMIC_RELAXED,
                       __HIP_MEMORY_SCOPE_AGENT);
    __hip_atomic_store(&g_flag[threadIdx.x].v, 0, __ATOMIC_RELAXED,
                       __HIP_MEMORY_SCOPE_AGENT);
  }
  int j = blockIdx.x * 16 + (threadIdx.x & 15);
  int i = blockIdx.y * 16 + (threadIdx.x >> 4);
  Ws[(size_t)i * N + j] = 0.5f * (W[(size_t)i * N + j] + W[(size_t)j * N + i]);
}

// ---------------------------------------------------------------------------
// x_proj = A (M x K) . B^T, B = W_input (N x K) row-major. 128x128 tile.
// XCD-aware swizzle: each XCD owns a contiguous bm chunk x all 8 bn.
// ---------------------------------------------------------------------------
__global__ __launch_bounds__(256) void xproj_gemm(const float* __restrict__ A,
                                                  const float* __restrict__ B,
                                                  float* __restrict__ C,
                                                  int M) {
  constexpr int BM = 128, BN = 128, BK = 16;
  __shared__ float As[BK][BM + 4];
  __shared__ float Bs[BK][BN + 4];

  const int tid = threadIdx.x;
  const int lin = blockIdx.x + gridDim.x * blockIdx.y;  // 0..2047
  const int sw  = ((lin & 7) << 8) + (lin >> 3);        // bijective (2048%8==0)
  const int bm  = sw >> 3;                              // 0..255
  const int bn  = sw & 7;                               // 0..7
  const int tx = tid & 15, ty = tid >> 4;
  const int K = N;

  float acc[8][8];
#pragma unroll
  for (int i = 0; i < 8; ++i)
#pragma unroll
    for (int j = 0; j < 8; ++j) acc[i][j] = 0.f;

  for (int kt = 0; kt < K; kt += BK) {
#pragma unroll
    for (int s = 0; s < 2; ++s) {
      int f = tid + s * 256;
      int row = f >> 2, kq = f & 3;
      float4 a = *reinterpret_cast<const float4*>(
          &A[(size_t)(bm * BM + row) * K + kt + kq * 4]);
      As[kq * 4 + 0][row] = a.x;
      As[kq * 4 + 1][row] = a.y;
      As[kq * 4 + 2][row] = a.z;
      As[kq * 4 + 3][row] = a.w;
      float4 b = *reinterpret_cast<const float4*>(
          &B[(size_t)(bn * BN + row) * K + kt + kq * 4]);
      Bs[kq * 4 + 0][row] = b.x;
      Bs[kq * 4 + 1][row] = b.y;
      Bs[kq * 4 + 2][row] = b.z;
      Bs[kq * 4 + 3][row] = b.w;
    }
    __syncthreads();

#pragma unroll
    for (int k = 0; k < BK; ++k) {
      float a[8], b[8];
      *reinterpret_cast<float4*>(&a[0]) =
          *reinterpret_cast<const float4*>(&As[k][ty * 8]);
      *reinterpret_cast<float4*>(&a[4]) =
          *reinterpret_cast<const float4*>(&As[k][ty * 8 + 4]);
      *reinterpret_cast<float4*>(&b[0]) =
          *reinterpret_cast<const float4*>(&Bs[k][tx * 8]);
      *reinterpret_cast<float4*>(&b[4]) =
          *reinterpret_cast<const float4*>(&Bs[k][tx * 8 + 4]);
#pragma unroll
      for (int i = 0; i < 8; ++i)
#pragma unroll
        for (int j = 0; j < 8; ++j) acc[i][j] = fmaf(a[i], b[j], acc[i][j]);
    }
    __syncthreads();
  }

#pragma unroll
  for (int i = 0; i < 8; ++i) {
    size_t row = (size_t)bm * BM + ty * 8 + i;
#pragma unroll
    for (int j = 0; j < 8; j += 4) {
      *reinterpret_cast<float4*>(&C[row * N + bn * BN + tx * 8 + j]) =
          *reinterpret_cast<const float4*>(&acc[i][j]);
    }
  }
}

// ---------------------------------------------------------------------------
// Persistent recurrence: R13 handshake, membership halved (16-WG barriers).
// 256 WGs x 640 thr (10 waves), 1 WG/CU (LDS ~85 KiB).  WG (p=wg&15,
// cg=wg>>4): cols m0=cg*64 for batch groups gA=2p, gB=2p+1 (2 batches each).
// Waves 0-7 compute (per thread: 2 batches x 2 cols x 16-way k-split;
// wreg[2][16] = 128 VGPR).  Wave 8/9: sync+stage for chain A/B (8 KB h +
// xp per step).  Handshake/order IDENTICAL to R13: spin ready -> compute ->
// store -> wait_vm0 -> LDS ack; sync wave: spin acks -> arrive -> poll ->
// stage -> ready.  Data path sc0+sc1 / nt write-through (MALL-coherent).
// ---------------------------------------------------------------------------
__global__ __launch_bounds__(640, 1) void rnn_persist(
    float* __restrict__ out, const float* __restrict__ Ws) {
  const int tid = threadIdx.x;
  const int wg  = blockIdx.x;
  const int p   = wg & 15;
  const int cg  = wg >> 4;
  const int m0  = cg * 64;
  const int gA  = 2 * p, gB = 2 * p + 1;
  const int b0A = gA * 2, b0B = gB * 2;
  const size_t TN = (size_t)T * N;

  // LDS: hA[2][1028] | hB[2][1028] | xplA[128] | xplB[128]; W staging
  // (8 rows x 1028) overlays the base.  Padded to force 1 WG/CU.
  __shared__ __align__(16) char lds_raw[84992];
  __shared__ int lflags[64];  // [0]=readyA [16]=readyB [32]=cntA [48]=cntB
  float (*hA)[1028] = reinterpret_cast<float(*)[1028]>(lds_raw);
  float (*hB)[1028] = reinterpret_cast<float(*)[1028]>(lds_raw + 8224);
  float* xplA = reinterpret_cast<float*>(lds_raw + 16448);
  float* xplB = reinterpret_cast<float*>(lds_raw + 17024);
  float (*Wq)[1028] = reinterpret_cast<float(*)[1028]>(lds_raw);

  if (tid == 0) {
    lflags[0] = -1; lflags[16] = -1; lflags[32] = 0; lflags[48] = 0;
  }
  __syncthreads();

  const int l  = tid & 63;
  const int v  = tid >> 6;          // 0-7 compute, 8-9 sync
  const int c2 = l & 3;
  const int kp = l >> 2;            // k partition (16-way)
  const int clocal = v * 8 + c2 * 2;  // compute waves: local col pair base

  // ---- W -> wreg in 8 quarters of 8 rows (overlay on h region) ----
  f4 wreg[2][16];
  for (int quarter = 0; quarter < 8; ++quarter) {
    if (tid < 256) {
#pragma unroll
      for (int q = 0; q < 8; ++q)
        *reinterpret_cast<float4*>(&Wq[q][tid * 4]) =
            *reinterpret_cast<const float4*>(
                &Ws[(size_t)(m0 + quarter * 8 + q) * N + tid * 4]);
    }
    __syncthreads();
    if (v == quarter) {
#pragma unroll
      for (int ci = 0; ci < 2; ++ci)
#pragma unroll
        for (int j = 0; j < 16; ++j)
          wreg[ci][j] =
              *reinterpret_cast<const f4*>(&Wq[c2 * 2 + ci][kp * 4 + 64 * j]);
    }
    __syncthreads();
  }

  if (v < 8) {
    // ================= COMPUTE WAVES =================
    float* obA[2];
    float* obB[2];
#pragma unroll
    for (int bi = 0; bi < 2; ++bi) {
      obA[bi] = out + (size_t)(b0A + bi) * TN + m0 + clocal;
      obB[bi] = out + (size_t)(b0B + bi) * TN + m0 + clocal;
    }

    auto do_chain = [&](float (*hX)[1028], float* xplX, float* const* obX,
                        int rdyIdx, int cntIdx, int t) {
      while (*(volatile int*)&lflags[rdyIdx] < t) __builtin_amdgcn_s_sleep(1);
      __builtin_amdgcn_fence(__ATOMIC_ACQUIRE, "workgroup");
      float acc[4];
#pragma unroll
      for (int i = 0; i < 4; ++i) acc[i] = 0.f;
      if (t > 0) {
#pragma unroll
        for (int j = 0; j < 16; ++j) {
          const int kb = kp * 4 + 64 * j;
          f4 hv[2];
#pragma unroll
          for (int bi = 0; bi < 2; ++bi)
            hv[bi] = *reinterpret_cast<const f4*>(&hX[bi][kb]);
#pragma unroll
          for (int bi = 0; bi < 2; ++bi)
#pragma unroll
            for (int ci = 0; ci < 2; ++ci) {
              float a = acc[bi * 2 + ci];
              a = fmaf(hv[bi].x, wreg[ci][j].x, a);
              a = fmaf(hv[bi].y, wreg[ci][j].y, a);
              a = fmaf(hv[bi].z, wreg[ci][j].z, a);
              a = fmaf(hv[bi].w, wreg[ci][j].w, a);
              acc[bi * 2 + ci] = a;
            }
        }
#pragma unroll
        for (int o = 4; o < 64; o <<= 1)
#pragma unroll
          for (int i = 0; i < 4; ++i) acc[i] += __shfl_xor(acc[i], o, 64);
      }
      if (kp == 0) {
#pragma unroll
        for (int bi = 0; bi < 2; ++bi) {
          float x0 = xplX[bi * 64 + clocal];
          float x1 = xplX[bi * 64 + clocal + 1];
          f2 r;
          r.x = tanhf((t > 0 ? acc[bi * 2 + 0] : 0.f) + x0);
          r.y = tanhf((t > 0 ? acc[bi * 2 + 1] : 0.f) + x1);
          st_sys_x2(obX[bi] + (size_t)t * N, r);
        }
      }
      wait_vm0();  // this wave's stores acked at MALL
      if (l == 0) atomicAdd(&lflags[cntIdx], 1);
    };

    for (int t = 0; t < T; ++t) {
      do_chain(hA, xplA, obA, 0, 32, t);
      do_chain(hB, xplB, obB, 16, 48, t);
    }
  } else {
    // ================= SYNC/STAGE WAVES =================
    const bool isB = (v == 9);
    const int lane = l;
    const int g    = isB ? gB : gA;
    const int b0   = isB ? b0B : b0A;
    float (*hb)[1028] = isB ? hB : hA;
    float* xpl = isB ? xplB : xplA;
    volatile int* ready = isB ? (volatile int*)&lflags[16]
                              : (volatile int*)&lflags[0];
    volatile int* cnt = isB ? (volatile int*)&lflags[48]
                            : (volatile int*)&lflags[32];

    const int r = lane >> 5;   // h row 0..1 (32 lanes per row)
    const int c = lane & 31;
    const float* hrow = out + (size_t)(b0 + r) * TN;
    const int xr = lane >> 4, xc = (lane & 15) * 4;  // lane<32: 2 rows x 64 col
    const float* xsrc = out + (size_t)(b0 + xr) * TN + m0 + xc;

    // stage xp(0); publish ready=0
    {
      f4 xv;
      if (lane < 32) xv = ld_sys_x4(xsrc);
      wait_vm0();
      if (lane < 32) *reinterpret_cast<f4*>(&xpl[xr * 64 + xc]) = xv;
      __builtin_amdgcn_fence(__ATOMIC_RELEASE, "workgroup");
      if (lane == 0) *ready = 0;
    }

    for (int t = 1; t < T; ++t) {
      if (lane == 0) {
        while (*cnt < 8 * t) __builtin_amdgcn_s_sleep(1);  // local acks(t-1)
        arrive_cnt(g, t - 1);                              // global arrive
        pollf(g, t);                                       // wait group done
      }
      // stage h(t-1) (8 KB) + xp(t), single vmcnt round
      const float* hs = hrow + (size_t)(t - 1) * N;
      f4 tmp[8];
      f4 xv;
#pragma unroll
      for (int q = 0; q < 8; ++q) tmp[q] = ld_sys_x4(hs + 4 * (c + 32 * q));
      if (lane < 32) xv = ld_sys_x4(xsrc + (size_t)t * N);
      wait_vm0();
#pragma unroll
      for (int q = 0; q < 8; ++q)
        *reinterpret_cast<f4*>(&hb[r][4 * (c + 32 * q)]) = tmp[q];
      if (lane < 32) *reinterpret_cast<f4*>(&xpl[xr * 64 + xc]) = xv;
      __builtin_amdgcn_fence(__ATOMIC_RELEASE, "workgroup");
      if (lane == 0) *ready = t;
    }
  }
}

// ---------------------------------------------------------------------------
extern "C" void kernel_launch(void* const* d_in, const int* in_sizes, int n_in,
                              void* d_out, int out_size, void* d_ws,
                              size_t ws_size, hipStream_t stream) {
  const float* in_seq  = (const float*)d_in[0];  // (64,512,1024)
  const float* W_lower = (const float*)d_in[1];  // (1024,1024)
  const float* W_input = (const float*)d_in[2];  // (1024,1024)
  float* out = (float*)d_out;                    // (64,512,1024)
  float* Ws  = (float*)d_ws;                     // 4 MiB scratch

  symm_k<<<dim3(N / 16, N / 16), 256, 0, stream>>>(W_lower, Ws);
  xproj_gemm<<<dim3(N / 128, (BATCH * T) / 128), 256, 0, stream>>>(
      in_seq, W_input, out, BATCH * T);
  rnn_persist<<<NWG, 640, 0, stream>>>(out, Ws);
}